// Round 8
// baseline (197.780 us; speedup 1.0000x reference)
//
#include <hip/hip_runtime.h>
#include <hip/hip_bf16.h>
#include <stdint.h>

#define S_LEN 4096

typedef short s16x8  __attribute__((ext_vector_type(8)));
typedef float f32x4  __attribute__((ext_vector_type(4)));
typedef float f32x16 __attribute__((ext_vector_type(16)));

// log2(e)/8 : folded into Q at QKV epilogue; attn does exp2(score) directly
#define CEXP 0.18033688011112042f

__device__ __forceinline__ unsigned short f2bf(float f) {
    union { float f; unsigned u; } v; v.f = f;
    unsigned r = v.u + 0x7fffu + ((v.u >> 16) & 1u);
    return (unsigned short)(r >> 16);
}

__device__ __forceinline__ ushort2 pkbf(float a, float b) {
    float2 f; f.x = a; f.y = b;
    __hip_bfloat162 h = __float22bfloat162_rn(f);
    union { __hip_bfloat162 h; ushort2 u; } cv; cv.h = h;
    return cv.u;
}

__device__ __forceinline__ ushort4 pkbf4(float x, float y, float z, float w) {
    ushort2 lo = pkbf(x, y), hi = pkbf(z, w);
    ushort4 r; r.x = lo.x; r.y = lo.y; r.z = hi.x; r.w = hi.y;
    return r;
}

__device__ __forceinline__ unsigned pku(float a, float b) {
    union { ushort2 s; unsigned u; } c; c.s = pkbf(a, b); return c.u;
}

typedef const __attribute__((address_space(1))) void* gas_t;
typedef __attribute__((address_space(3))) void* sas_t;

__device__ __forceinline__ void async16(const void* g, void* s) {
    __builtin_amdgcn_global_load_lds((gas_t)g, (sas_t)s, 16, 0, 0);
}

// ---------------------------------------------------------------------------
// fp32 -> bf16 convert for X (4194304) and W (3145728). 8 elems/thread.
// ---------------------------------------------------------------------------
__global__ __launch_bounds__(256) void cvt_bf16(
    const float* __restrict__ X, const float* __restrict__ W,
    unsigned short* __restrict__ Xb, unsigned short* __restrict__ Wb)
{
    const long NX = 4194304;
    long i = (long)(blockIdx.x * 256 + threadIdx.x) * 8;
    const float* src; unsigned short* dst; long off;
    if (i < NX) { src = X; dst = Xb; off = i; }
    else        { src = W; dst = Wb; off = i - NX; }
    float4 a = *(const float4*)(src + off);
    float4 b = *(const float4*)(src + off + 4);
    union { s16x8 v; ushort4 q[2]; } o;
    o.q[0] = pkbf4(a.x, a.y, a.z, a.w);
    o.q[1] = pkbf4(b.x, b.y, b.z, b.w);
    *(s16x8*)(dst + off) = o.v;
}

// ---------------------------------------------------------------------------
// Kernel A (primary): qkv = Xb @ Wb^T + b, bf16 in. (R7 version, unchanged)
// BK=32 dbuf (2x16KB staging, 34816B LDS block) -> 4 blocks/CU, all 768
// blocks resident, 1 barrier/kt. Vectorized Q/K epilogue.
// ---------------------------------------------------------------------------
__global__ __launch_bounds__(256) void qkv_gemm_bf16(
    const unsigned short* __restrict__ Xb, const unsigned short* __restrict__ Wb,
    const float* __restrict__ bias, const float* __restrict__ trace,
    unsigned short* __restrict__ Qb, unsigned short* __restrict__ Kb,
    unsigned short* __restrict__ Vt)
{
    __shared__ __align__(16) unsigned short sm[17408];   // 34816 B

    const int t = threadIdx.x;
    const int l = t & 63;
    const int w = t >> 6;
    const int bm = blockIdx.y, bn = blockIdx.x;
    const int rowBase = (w >> 1) * 64;
    const int colBase = (w & 1) * 64;

    f32x4 acc[4][4];
#pragma unroll
    for (int i = 0; i < 4; i++)
#pragma unroll
        for (int j = 0; j < 4; j++) acc[i][j] = (f32x4)0.f;

    const int p0 = w * 128 + l;
    const int p1 = p0 + 64;
    const int ar0 = p0 >> 2, ac0 = (p0 & 3) * 8;
    const int ar1 = p1 >> 2, ac1 = (p1 & 3) * 8;

    async16(Xb + (bm * 128 + ar0) * 1024 + ac0, sm + p0 * 8);
    async16(Xb + (bm * 128 + ar1) * 1024 + ac1, sm + p1 * 8);
    async16(Wb + (bn * 128 + ar0) * 1024 + ac0, sm + 4096 + p0 * 8);
    async16(Wb + (bn * 128 + ar1) * 1024 + ac1, sm + 4096 + p1 * 8);

    for (int kt = 0; kt < 32; ++kt) {
        __syncthreads();
        const unsigned short* As = sm + (kt & 1) * 8192;
        const unsigned short* Bs = As + 4096;

        if (kt < 31) {
            const int k0 = (kt + 1) * 32;
            unsigned short* An = sm + ((kt + 1) & 1) * 8192;
            async16(Xb + (bm * 128 + ar0) * 1024 + k0 + ac0, An + p0 * 8);
            async16(Xb + (bm * 128 + ar1) * 1024 + k0 + ac1, An + p1 * 8);
            async16(Wb + (bn * 128 + ar0) * 1024 + k0 + ac0, An + 4096 + p0 * 8);
            async16(Wb + (bn * 128 + ar1) * 1024 + k0 + ac1, An + 4096 + p1 * 8);
        }

        s16x8 af[4], bf[4];
#pragma unroll
        for (int i = 0; i < 4; i++) {
            af[i] = *(const s16x8*)(As + (rowBase + i * 16 + (l & 15)) * 32 + (l >> 4) * 8);
            bf[i] = *(const s16x8*)(Bs + (colBase + i * 16 + (l & 15)) * 32 + (l >> 4) * 8);
        }
#pragma unroll
        for (int i = 0; i < 4; i++)
#pragma unroll
            for (int j = 0; j < 4; j++)
                acc[i][j] = __builtin_amdgcn_mfma_f32_16x16x32_bf16(af[i], bf[j], acc[i][j], 0, 0, 0);
    }

    __syncthreads();

    if (bn < 16) {
        unsigned short* Ls = sm;                  // [128 s][136 c]
        const int region = bn >> 3;
        unsigned short* dst = region ? Kb : Qb;
        const float scl = region ? 1.0f : CEXP;
#pragma unroll
        for (int j = 0; j < 4; j++) {
            int cl = colBase + j * 16 + (l & 15);
            float bv = bias[bn * 128 + cl];
#pragma unroll
            for (int i = 0; i < 4; i++) {
                int s0 = rowBase + i * 16 + ((l >> 4) << 2);
#pragma unroll
                for (int r = 0; r < 4; r++)
                    Ls[(s0 + r) * 136 + cl] = f2bf((acc[i][j][r] + bv) * scl);
            }
        }
        __syncthreads();
#pragma unroll
        for (int p = 0; p < 8; ++p) {
            int tk = p * 256 + t;
            int s  = tk >> 4;
            int ch = tk & 15;
            int gc = bn * 128 + ch * 8;
            int h  = (gc >> 6) & 15, d = gc & 63;
            s16x8 v = *(const s16x8*)(Ls + s * 136 + ch * 8);
            *(s16x8*)(dst + (h * S_LEN + bm * 128 + s) * 64 + d) = v;
        }
    } else {
        unsigned short* Lt = sm;              // 128 x 136
#pragma unroll
        for (int j = 0; j < 4; j++) {
            int cl = colBase + j * 16 + (l & 15);
            int o  = bn * 128 + cl - 2048;
            float bv = bias[bn * 128 + cl];
            float tr = trace[(o >> 6) * 4096 + (o & 63) * 65];
#pragma unroll
            for (int i = 0; i < 4; i++) {
                int s0 = rowBase + i * 16 + ((l >> 4) << 2);
                *(ushort4*)(Lt + cl * 136 + s0) =
                    pkbf4((acc[i][j][0] + bv) * tr, (acc[i][j][1] + bv) * tr,
                          (acc[i][j][2] + bv) * tr, (acc[i][j][3] + bv) * tr);
            }
        }
        __syncthreads();
#pragma unroll
        for (int p = 0; p < 8; ++p) {
            int dl  = (t >> 4) + p * 16;
            int sch = (t & 15) * 8;
            int o = bn * 128 + dl - 2048;
            int h = o >> 6, d = o & 63;
            s16x8 v = *(const s16x8*)(Lt + dl * 136 + sch);
            *(s16x8*)(Vt + (h * 64 + d) * S_LEN + bm * 128 + sch) = v;
        }
    }
}

// ---------------------------------------------------------------------------
// Kernel A (fallback, small ws): fp32-staged GEMM, same outputs (unchanged)
// ---------------------------------------------------------------------------
__global__ __launch_bounds__(256) void qkv_gemm_f32(
    const float* __restrict__ X, const float* __restrict__ W,
    const float* __restrict__ bias, const float* __restrict__ trace,
    unsigned short* __restrict__ Qb, unsigned short* __restrict__ Kb,
    unsigned short* __restrict__ Vt)
{
    __shared__ __align__(16) unsigned short sm[17408];
    unsigned short* As = sm;
    unsigned short* Bs = sm + 5120;

    const int t = threadIdx.x;
    const int l = t & 63;
    const int w = t >> 6;
    const int bm = blockIdx.y, bn = blockIdx.x;
    const int rowBase = (w >> 1) * 64;
    const int colBase = (w & 1) * 64;

    f32x4 acc[4][4];
#pragma unroll
    for (int i = 0; i < 4; i++)
#pragma unroll
        for (int j = 0; j < 4; j++) acc[i][j] = (f32x4)0.f;

    const int sr = t >> 3;
    const int sc = (t & 7) * 4;

    for (int kt = 0; kt < 32; ++kt) {
        const int k0 = kt * 32;
#pragma unroll
        for (int p = 0; p < 4; ++p) {
            int r = sr + p * 32;
            float4 xa = *(const float4*)(X + (bm * 128 + r) * 1024 + k0 + sc);
            float4 wb = *(const float4*)(W + (bn * 128 + r) * 1024 + k0 + sc);
            *(ushort4*)(As + r * 40 + sc) = pkbf4(xa.x, xa.y, xa.z, xa.w);
            *(ushort4*)(Bs + r * 40 + sc) = pkbf4(wb.x, wb.y, wb.z, wb.w);
        }
        __syncthreads();

        s16x8 af[4], bf[4];
#pragma unroll
        for (int i = 0; i < 4; i++) {
            af[i] = *(const s16x8*)(As + (rowBase + i * 16 + (l & 15)) * 40 + (l >> 4) * 8);
            bf[i] = *(const s16x8*)(Bs + (colBase + i * 16 + (l & 15)) * 40 + (l >> 4) * 8);
        }
#pragma unroll
        for (int i = 0; i < 4; i++)
#pragma unroll
            for (int j = 0; j < 4; j++)
                acc[i][j] = __builtin_amdgcn_mfma_f32_16x16x32_bf16(af[i], bf[j], acc[i][j], 0, 0, 0);
        __syncthreads();
    }

    if (bn < 16) {
#pragma unroll
        for (int j = 0; j < 4; j++) {
            int col = bn * 128 + colBase + j * 16 + (l & 15);
            float bv = bias[col];
            int region = col >> 10;
            int within = col & 1023;
            int h = within >> 6, d = within & 63;
            unsigned short* dst = (region == 0) ? Qb : Kb;
            float scl = (region == 0) ? CEXP : 1.0f;
#pragma unroll
            for (int i = 0; i < 4; i++) {
                int s0 = bm * 128 + rowBase + i * 16 + ((l >> 4) << 2);
#pragma unroll
                for (int r = 0; r < 4; r++)
                    dst[(h * S_LEN + s0 + r) * 64 + d] = f2bf((acc[i][j][r] + bv) * scl);
            }
        }
    } else {
        __syncthreads();
        unsigned short* Lt = sm;
#pragma unroll
        for (int j = 0; j < 4; j++) {
            int cl = colBase + j * 16 + (l & 15);
            int o  = bn * 128 + cl - 2048;
            float bv = bias[bn * 128 + cl];
            float tr = trace[(o >> 6) * 4096 + (o & 63) * 65];
#pragma unroll
            for (int i = 0; i < 4; i++) {
                int s0 = rowBase + i * 16 + ((l >> 4) << 2);
                *(ushort4*)(Lt + cl * 136 + s0) =
                    pkbf4((acc[i][j][0] + bv) * tr, (acc[i][j][1] + bv) * tr,
                          (acc[i][j][2] + bv) * tr, (acc[i][j][3] + bv) * tr);
            }
        }
        __syncthreads();
#pragma unroll
        for (int p = 0; p < 8; ++p) {
            int dl  = (t >> 4) + p * 16;
            int sch = (t & 15) * 8;
            int o = bn * 128 + dl - 2048;
            int h = o >> 6, d = o & 63;
            s16x8 v = *(const s16x8*)(Lt + dl * 136 + sch);
            *(s16x8*)(Vt + (h * 64 + d) * S_LEN + bm * 128 + sch) = v;
        }
    }
}

// ---------------------------------------------------------------------------
// attn staging source-address helper: physical 16B slot p in a group's
// padded tile-pair (K [64][72] at slots 0..575, V [64][72] at 576..1151).
// slot byte = p*16 = row*144 + chunk*16; chunk 8 = pad (re-loads chunk 0,
// never read back: reads stay within shorts [0,64) of each 72-short row).
// ---------------------------------------------------------------------------
__device__ __forceinline__ const unsigned short* kv_src(
    int p, int h, int g,
    const unsigned short* __restrict__ Kb,
    const unsigned short* __restrict__ Vt)
{
    const bool isK = (p < 576);
    const int q = isK ? p : (p - 576);
    const int row = q / 9;              // magic-mul div
    const int c = q - row * 9;
    const int cc = (c < 8) ? c : 0;     // pad slot -> harmless duplicate
    return isK ? (Kb + (h * S_LEN + g * 2048 + row) * 64 + cc * 8)
               : (Vt + (h * 64 + row) * S_LEN + g * 2048 + cc * 8);
}

// ---------------------------------------------------------------------------
// Kernel B: flash attention. R8 change (vs R7 88.8 µs version):
// K/V LDS layout linear-[64][64]+XOR -> padded [64][72] (stride-72 rows),
// staged via DMA with the pad-slot trick. R0 measured this read pattern at
// 131K bank conflicts (vs 8.52M for the XOR layout) with identical reads;
// DMA dbuf mechanics unchanged (R2/R5/R6/R7-proven). Reads lose the XOR ->
// loop-invariant addresses. 18 DMA wave-instrs per group-tile: waves 0,1
// issue 5, waves 2,3 issue 4 (wave-uniform). LDS 70656 -> 74752 B (still
// 2 blocks/CU, grid-capped at 2 anyway). T12 / setprio / epilogue unchanged.
// ---------------------------------------------------------------------------
__global__ __launch_bounds__(512, 4) void attn(
    const unsigned short* __restrict__ Qb, const unsigned short* __restrict__ Kb,
    const unsigned short* __restrict__ Vt, float* __restrict__ out)
{
    __shared__ __align__(16) unsigned short sm[36864];   // 73728 B: [buf][grp][K|V] padded
    __shared__ float lArr[256];

    const int t = threadIdx.x;
    const int l = t & 63;
    const int w = t >> 6;            // 0..7
    const int g = w >> 2;            // kv half
    const int wg = w & 3;            // wave within group
    const int wq = w & 3;            // q sub-tile
    // XCD swizzle: xcd = bid%8 owns heads {2*xcd, 2*xcd+1}
    const int bid = blockIdx.x;
    const int xcd = bid & 7;
    const int j   = bid >> 3;        // 0..63
    const int h   = xcd * 2 + (j & 1);
    const int qblk = j >> 1;         // 0..31
    const int qbase = qblk * 128 + wq * 32;
    const int l31 = l & 31;
    const int lh  = l >> 5;

    s16x8 qf[4];
#pragma unroll
    for (int ks = 0; ks < 4; ks++)
        qf[ks] = *(const s16x8*)(Qb + (h * S_LEN + qbase + l31) * 64 + ks * 16 + lh * 8);

    f32x16 O0 = (f32x16)0.f, O1 = (f32x16)0.f;
    float2 lpA; lpA.x = 0.f; lpA.y = 0.f;
    float2 lpB; lpB.x = 0.f; lpB.y = 0.f;

    // --- DMA staging: wave wg issues instrs {wg, wg+4, wg+8, wg+12} and,
    // for wg<2, also {16+wg}. Instr i covers slots [i*64, i*64+64).
    // Slots 0..575 = K (advance 4096 shorts/kt), 576..1151 = V (advance 64).
    // Instr 8 (wg==0 slot 2) is the only mixed-ownership case: K.
    const unsigned short* gp0 = kv_src((wg + 0)  * 64 + l, h, g, Kb, Vt);
    const unsigned short* gp1 = kv_src((wg + 4)  * 64 + l, h, g, Kb, Vt);
    const unsigned short* gp2 = kv_src((wg + 8)  * 64 + l, h, g, Kb, Vt);
    const unsigned short* gp3 = kv_src((wg + 12) * 64 + l, h, g, Kb, Vt);
    const unsigned short* gp4 = (wg < 2) ? kv_src((wg + 16) * 64 + l, h, g, Kb, Vt) : gp3;
    const int a2 = (wg == 0) ? 4096 : 64;   // instr 8 is K; instrs 9..11 are V
    const int d0 = (wg + 0)  * 512 + l * 8;  // dst offsets in shorts (16B/lane)
    const int d1 = (wg + 4)  * 512 + l * 8;
    const int d2 = (wg + 8)  * 512 + l * 8;
    const int d3 = (wg + 12) * 512 + l * 8;
    const int d4 = (wg + 16) * 512 + l * 8;

    // prologue: stage tile 0 into buf 0
    {
        unsigned short* tb = sm + g * 9216;
        async16(gp0, tb + d0);
        async16(gp1, tb + d1);
        async16(gp2, tb + d2);
        async16(gp3, tb + d3);
        if (wg < 2) async16(gp4, tb + d4);
    }

    for (int kt = 0; kt < 32; ++kt) {
        __syncthreads();   // implicit vmcnt(0): buf[kt&1] DMA done everywhere;
                           // all waves finished reading buf[kt&1 ^ 1]
        const unsigned short* sb  = sm + ((kt & 1) * 2 + g) * 9216;   // K [64][72]
        const unsigned short* vbs = sb + 4608;                        // V [64][72]

        // issue next tile's DMA into the other buffer (zero staging registers)
        if (kt < 31) {
            gp0 += 4096; gp1 += 4096; gp2 += a2; gp3 += 64; gp4 += 64;
            unsigned short* tb = sm + (((kt + 1) & 1) * 2 + g) * 9216;
            async16(gp0, tb + d0);
            async16(gp1, tb + d1);
            async16(gp2, tb + d2);
            async16(gp3, tb + d3);
            if (wg < 2) async16(gp4, tb + d4);
        }

        // S^T[kv][q] = K x Q^T  (scores pre-scaled via Q); stride-72 reads
        f32x16 S0 = (f32x16)0.f, S1 = (f32x16)0.f;
        __builtin_amdgcn_s_setprio(1);
#pragma unroll
        for (int ks = 0; ks < 4; ks++) {
            s16x8 a0 = *(const s16x8*)(sb + l31 * 72 + ks * 16 + lh * 8);
            s16x8 a1 = *(const s16x8*)(sb + (32 + l31) * 72 + ks * 16 + lh * 8);
            S0 = __builtin_amdgcn_mfma_f32_32x32x16_bf16(a0, qf[ks], S0, 0, 0, 0);
            S1 = __builtin_amdgcn_mfma_f32_32x32x16_bf16(a1, qf[ks], S1, 0, 0, 0);
        }
        __builtin_amdgcn_s_setprio(0);

#pragma unroll
        for (int i = 0; i < 16; i += 4) {
            float p0v = __builtin_amdgcn_exp2f(S0[i+0]); S0[i+0] = p0v; lpA.x += p0v;
            float p1v = __builtin_amdgcn_exp2f(S0[i+1]); S0[i+1] = p1v; lpA.y += p1v;
            float p2v = __builtin_amdgcn_exp2f(S0[i+2]); S0[i+2] = p2v; lpB.x += p2v;
            float p3v = __builtin_amdgcn_exp2f(S0[i+3]); S0[i+3] = p3v; lpB.y += p3v;
        }
#pragma unroll
        for (int i = 0; i < 16; i += 4) {
            float p0v = __builtin_amdgcn_exp2f(S1[i+0]); S1[i+0] = p0v; lpA.x += p0v;
            float p1v = __builtin_amdgcn_exp2f(S1[i+1]); S1[i+1] = p1v; lpA.y += p1v;
            float p2v = __builtin_amdgcn_exp2f(S1[i+2]); S1[i+2] = p2v; lpB.x += p2v;
            float p3v = __builtin_amdgcn_exp2f(S1[i+3]); S1[i+3] = p3v; lpB.y += p3v;
        }

        // T12: O^T[d][q] += V^T x P^T, P built in-register (R1-verified map).
        __builtin_amdgcn_s_setprio(1);
#define PVBLK(SX, BO, KS) do {                                               \
        unsigned pa0 = pku(SX[(BO)+0], SX[(BO)+1]);                          \
        unsigned pc0 = pku(SX[(BO)+4], SX[(BO)+5]);                          \
        unsigned pa1 = pku(SX[(BO)+2], SX[(BO)+3]);                          \
        unsigned pc1 = pku(SX[(BO)+6], SX[(BO)+7]);                          \
        auto r0 = __builtin_amdgcn_permlane32_swap(pa0, pc0, false, false);  \
        auto r1 = __builtin_amdgcn_permlane32_swap(pa1, pc1, false, false);  \
        union { s16x8 v; unsigned u[4]; } pb_;                               \
        pb_.u[0] = r0[0]; pb_.u[1] = r1[0]; pb_.u[2] = r0[1]; pb_.u[3] = r1[1]; \
        s16x8 av0 = *(const s16x8*)(vbs + l31 * 72 + (KS) * 16 + lh * 8);    \
        s16x8 av1 = *(const s16x8*)(vbs + (32 + l31) * 72 + (KS) * 16 + lh * 8); \
        O0 = __builtin_amdgcn_mfma_f32_32x32x16_bf16(av0, pb_.v, O0, 0, 0, 0); \
        O1 = __builtin_amdgcn_mfma_f32_32x32x16_bf16(av1, pb_.v, O1, 0, 0, 0); \
    } while (0)
        PVBLK(S0, 0, 0);
        PVBLK(S0, 8, 1);
        PVBLK(S1, 0, 2);
        PVBLK(S1, 8, 3);
#undef PVBLK
        __builtin_amdgcn_s_setprio(0);
    }

    // per-wave l partial for q = qbase + l31
    float l_part = (lpA.x + lpA.y) + (lpB.x + lpB.y);
    float l_tot = l_part + __shfl_xor(l_part, 32);
    if (lh == 0) lArr[w * 32 + l31] = l_tot;

    __syncthreads();    // drain last PV's LDS reads before Lo overwrites sm

    // stash raw O^T (fp32) per wave: Lo[w][q 0..31][d 0..67(pad)]
    float* Lo = (float*)sm + w * 2176;
#pragma unroll
    for (int dt = 0; dt < 2; ++dt) {
        const f32x16& Ox = dt ? O1 : O0;
#pragma unroll
        for (int gq = 0; gq < 4; ++gq) {
            int d0f = dt * 32 + gq * 8 + lh * 4;
            float4 vv;
            vv.x = Ox[gq*4+0]; vv.y = Ox[gq*4+1]; vv.z = Ox[gq*4+2]; vv.w = Ox[gq*4+3];
            *(float4*)(Lo + l31 * 68 + d0f) = vv;
        }
    }
    __syncthreads();

    // waves 0-3: combine the two kv-half partials, normalize, store
    if (w < 4) {
        const float* LoA = (float*)sm + w * 2176;
        const float* LoB = (float*)sm + (w + 4) * 2176;
#pragma unroll
        for (int it = 0; it < 8; ++it) {
            int ql = it * 4 + (l >> 4);
            float invl = 1.0f / (lArr[w * 32 + ql] + lArr[(w + 4) * 32 + ql]);
            float4 a = *(const float4*)(LoA + ql * 68 + (l & 15) * 4);
            float4 b = *(const float4*)(LoB + ql * 68 + (l & 15) * 4);
            float4 vv;
            vv.x = (a.x + b.x) * invl;
            vv.y = (a.y + b.y) * invl;
            vv.z = (a.z + b.z) * invl;
            vv.w = (a.w + b.w) * invl;
            *(float4*)(out + (qblk * 128 + w * 32 + ql) * 1024 + h * 64 + (l & 15) * 4) = vv;
        }
    }
}

extern "C" void kernel_launch(void* const* d_in, const int* in_sizes, int n_in,
                              void* d_out, int out_size, void* d_ws, size_t ws_size,
                              hipStream_t stream) {
    const float* X     = (const float*)d_in[0];   // [1,4096,1024]
    const float* W     = (const float*)d_in[1];   // [3072,1024]
    const float* bias  = (const float*)d_in[2];   // [3072]
    const float* trace = (const float*)d_in[3];   // [16,64,64]
    float* out = (float*)d_out;

    unsigned short* Qb = (unsigned short*)d_ws;            // 8 MiB [h][s][d] (pre-scaled by CEXP)
    unsigned short* Kb = Qb + 4194304;                     // 8 MiB [h][s][d]
    unsigned short* Vt = Kb + 4194304;                     // 8 MiB [h][d][s] (pre-scaled by trace diag)
    unsigned short* Xb = Vt + 4194304;                     // 8 MiB bf16 X
    unsigned short* Wb = Xb + 4194304;                     // 6 MiB bf16 W

    const size_t NEED_BF16 = (size_t)3 * 8388608 + 8388608 + 6291456;

    if (ws_size >= NEED_BF16) {
        cvt_bf16<<<3584, 256, 0, stream>>>(X, W, Xb, Wb);
        qkv_gemm_bf16<<<dim3(24, 32), 256, 0, stream>>>(Xb, Wb, bias, trace, Qb, Kb, Vt);
    } else {
        qkv_gemm_f32<<<dim3(24, 32), 256, 0, stream>>>(X, W, bias, trace, Qb, Kb, Vt);
    }
    attn<<<512, 512, 0, stream>>>(Qb, Kb, Vt, out);
}